// Round 14
// baseline (868.590 us; speedup 1.0000x reference)
//
#include <hip/hip_runtime.h>
#include <hip/hip_bf16.h>

// SNN: B=128, T=16, IN=2048, HID=2048, OUT=1024; 256 total steps.
//   wsplit_i8: W2 -> 4x i8 fixed-point split: w = 2^-5 * sum q_s * 2^-7(s+1),
//              residual <= 5.8e-11/weight (worst-case dot err 1.2e-7)
//   Z1 = X @ W1^T + b1          (fp32 VALU GEMM v3: BK=32, conflict-free writes,
//                                k-order ascending -> bit-identical to R10/R11)
//   rec1: layer-1 recurrence -> bit-packed spikes (8.4 MB)
//   per 64-step chunk: gemm2_i8 (mfma_i32_16x16x64_i8, A=bits unpacked to i8,
//                      2 passes x 2 splits, exact i32 accumulation), then rec2.
// ws layout (~51.4 MB < 59.8 proven):
//   [0, 33.5M): Z1 (phase 1) / Z2c (chunks)  [33.5M: Sbits 8.4M]
//   [41.9M: W2q 4 x 2MB i8]  [50.3M: m_state/s_state 1M]
constexpr int B   = 128;
constexpr int T   = 16;
constexpr int IN  = 2048;
constexpr int HID = 2048;
constexpr int OUT = 1024;
constexpr int TAU = 256;
constexpr int CHUNK = 64;
constexpr float DECAY  = 0.2f;
constexpr float THRESH = 0.5f;

typedef int    v4i   __attribute__((ext_vector_type(4)));
typedef float  f32x4 __attribute__((ext_vector_type(4)));

// async global->LDS, 16B per lane. dest must be the wave-uniform base.
__device__ __forceinline__ void gload_lds16(const void* g, void* l) {
    __builtin_amdgcn_global_load_lds(
        (const __attribute__((address_space(1))) void*)g,
        (__attribute__((address_space(3))) void*)l, 16, 0, 0);
}

// ------------- wsplit_i8: fc2_w -> 4-level i8 fixed point ------------------
// w = 2^-5 * (q0*2^-7 + q1*2^-14 + q2*2^-21 + q3*2^-28) + eps, |eps|<=5.8e-11
// max |w| = 1/sqrt(2048) = 0.0221 < 2^-5 -> |q0|<=91, |q1..3|<=64 (fit i8).
// Each v*128 is exact (pow2); v*128-q is exact (Sterbenz) -> decomposition exact.
__global__ __launch_bounds__(256)
void wsplit_i8(const float* __restrict__ W, signed char* __restrict__ Q)
{
    const size_t SZ = (size_t)OUT * HID;
    int i = blockIdx.x * 256 + threadIdx.x;           // 4 elements per thread
    float4 w = *(const float4*)(W + (size_t)i * 4);
    float wv[4] = { w.x, w.y, w.z, w.w };
    signed char q[4][4];
    #pragma unroll
    for (int j = 0; j < 4; j++) {
        float v = wv[j] * 32.0f;                      // w / 2^-5
        float q0 = rintf(v * 128.f); v = v * 128.f - q0;
        float q1 = rintf(v * 128.f); v = v * 128.f - q1;
        float q2 = rintf(v * 128.f); v = v * 128.f - q2;
        float q3 = rintf(v * 128.f);
        q[0][j] = (signed char)(int)q0;
        q[1][j] = (signed char)(int)q1;
        q[2][j] = (signed char)(int)q2;
        q[3][j] = (signed char)(int)q3;
    }
    #pragma unroll
    for (int s = 0; s < 4; s++) {
        char4 c; c.x = q[s][0]; c.y = q[s][1]; c.z = q[s][2]; c.w = q[s][3];
        *(char4*)(Q + s * SZ + (size_t)i * 4) = c;
    }
}

// ---------------- GEMM1 v3: fp32 VALU, 64x64 tile, BK=32 -------------------
// Staging writer: row = tid&63, kq = tid>>6 (wave-uniform) -> lane-stride-1
// LDS writes, conflict-free. k ascending -> Z1 bit-identical to v1/v2.
__global__ __launch_bounds__(256, 4)
void gemm1_f32v3(const float* __restrict__ A, const float* __restrict__ W,
                 const float* __restrict__ bias, float* __restrict__ C,
                 int M, int N, int K)
{
    __shared__ float As[32][68];
    __shared__ float Bs[32][68];
    const int tid = threadIdx.x;
    const int tx = tid & 15, ty = tid >> 4;
    const int row0 = blockIdx.y * 64, col0 = blockIdx.x * 64;

    float acc[4][4];
    #pragma unroll
    for (int i = 0; i < 4; i++)
        #pragma unroll
        for (int j = 0; j < 4; j++) acc[i][j] = 0.f;

    const int sr = tid & 63;          // tile row
    const int kq = tid >> 6;          // k-quarter (wave-uniform): k off = kq*8

    for (int k0 = 0; k0 < K; k0 += 32) {
        const float* pa = A + (size_t)(row0 + sr) * K + k0 + kq * 8;
        const float* pb = W + (size_t)(col0 + sr) * K + k0 + kq * 8;
        float4 av0 = *(const float4*)pa, av1 = *(const float4*)(pa + 4);
        float4 bv0 = *(const float4*)pb, bv1 = *(const float4*)(pb + 4);
        __syncthreads();
        float avr[8] = { av0.x, av0.y, av0.z, av0.w, av1.x, av1.y, av1.z, av1.w };
        float bvr[8] = { bv0.x, bv0.y, bv0.z, bv0.w, bv1.x, bv1.y, bv1.z, bv1.w };
        #pragma unroll
        for (int i = 0; i < 8; i++) {
            As[kq * 8 + i][sr] = avr[i];
            Bs[kq * 8 + i][sr] = bvr[i];
        }
        __syncthreads();
        #pragma unroll
        for (int k = 0; k < 32; k++) {
            float4 a = *(const float4*)&As[k][ty * 4];
            float4 b = *(const float4*)&Bs[k][tx * 4];
            float ar[4] = { a.x, a.y, a.z, a.w };
            float br[4] = { b.x, b.y, b.z, b.w };
            #pragma unroll
            for (int i = 0; i < 4; i++)
                #pragma unroll
                for (int j = 0; j < 4; j++)
                    acc[i][j] = fmaf(ar[i], br[j], acc[i][j]);
        }
    }
    #pragma unroll
    for (int i = 0; i < 4; i++) {
        size_t r = (size_t)(row0 + ty * 4 + i);
        int c0 = col0 + tx * 4;
        float4 o;
        o.x = acc[i][0] + bias[c0 + 0];
        o.y = acc[i][1] + bias[c0 + 1];
        o.z = acc[i][2] + bias[c0 + 2];
        o.w = acc[i][3] + bias[c0 + 3];
        *(float4*)(C + r * N + c0) = o;
    }
}

// ---------------- rec1: layer-1 recurrence, bit-packed spikes --------------
__global__ __launch_bounds__(256)
void rec1(const float* __restrict__ Z1, unsigned long long* __restrict__ Sbits)
{
    int idx = blockIdx.x * 256 + threadIdx.x;   // b*HID + h
    int h = idx & (HID - 1);
    int b = idx >> 11;
    float z[16];
    #pragma unroll
    for (int t = 0; t < 16; t++)
        z[t] = Z1[((size_t)(b * T + t)) * HID + h];
    const size_t wbase = (size_t)b * (HID / 64) + (h >> 6);
    const bool lead = (threadIdx.x & 63) == 0;
    float m = 0.f, s = 0.f;
    for (int tau = 0; tau < TAU; ++tau) {
        m = m * DECAY * (1.f - s) + z[tau & 15];
        unsigned long long mask = __ballot(m > THRESH);
        s = (m > THRESH) ? 1.f : 0.f;
        if (lead)
            Sbits[(size_t)tau * (B * HID / 64) + wbase] = mask;
    }
}

// ---------------- GEMM2: i8 MFMA, A = spike bits, B = 4-split i8 W2 --------
// Tile 128x128, 4 waves (2x2 of 64x64), K-step 64, mfma_i32_16x16x64_i8.
// 2 passes x 2 splits; i32 accumulation exact; combine with pow2 scales.
// LDS fragment order: slot(g,kg,r) 16B = row/col g*16+r, k kg*16..+16.
__global__ __launch_bounds__(256, 2)
void gemm2_i8(const unsigned char* __restrict__ Sbytes,   // [TAU*B][256] bits
              const signed char* __restrict__ W2q,        // [4][OUT][HID] i8
              const float* __restrict__ bias,
              float* __restrict__ C,                      // [CHUNK*B][OUT]
              int m0glob)
{
    __shared__ unsigned char As8[8192];        //  8 KB: [8 g][4 kg][16 r][16 i8]
    __shared__ unsigned char Bs8[2][8192];     // 16 KB: 2 splits, same layout
    const size_t SZ = (size_t)OUT * HID;
    const int tid = threadIdx.x;
    const int l  = tid & 63, w = tid >> 6;
    const int wr = w >> 1, wc = w & 1;         // wave 2x2 grid
    const int lg = l >> 4, lr = l & 15;
    const int row0 = blockIdx.y * 128, col0 = blockIdx.x * 128;

    f32x4 master[4][4];
    #pragma unroll
    for (int m = 0; m < 4; m++)
        #pragma unroll
        for (int n = 0; n < 4; n++) master[m][n] = (f32x4){0.f, 0.f, 0.f, 0.f};

    // A staging: thread covers slots tid and tid+256 (g and g+4)
    const int gA = tid >> 6, kgA = (tid >> 4) & 3, rA = tid & 15;
    const size_t arow0 = (size_t)(m0glob + row0 + gA * 16 + rA) * 256 + kgA * 2;
    const size_t arow1 = (size_t)(m0glob + row0 + (gA + 4) * 16 + rA) * 256 + kgA * 2;
    unsigned char* aw0 = &As8[(size_t)tid * 16];
    unsigned char* aw1 = &As8[(size_t)(tid + 256) * 16];

    // B staging: wave w stages split (w>>1); sub-half (w&1); 4 iters x 64 slots
    const int spl = w >> 1, sub = w & 1;
    unsigned char* bbase = &Bs8[spl][0];
    const int bcol = col0 + (l & 15);
    const int bks  = ((l >> 4) & 3) * 16;

    for (int pass = 0; pass < 2; ++pass) {
        const signed char* wp = W2q + (size_t)(2 * pass + spl) * SZ;
        v4i acc0[4][4], acc1[4][4];
        #pragma unroll
        for (int m = 0; m < 4; m++)
            #pragma unroll
            for (int n = 0; n < 4; n++) {
                acc0[m][n] = (v4i){0, 0, 0, 0};
                acc1[m][n] = (v4i){0, 0, 0, 0};
            }

        for (int k0 = 0; k0 < HID; k0 += 64) {
            unsigned int bits0 = *(const unsigned short*)(Sbytes + arow0 + (k0 >> 3));
            unsigned int bits1 = *(const unsigned short*)(Sbytes + arow1 + (k0 >> 3));
            __syncthreads();                   // prior MFMA LDS reads done
            #pragma unroll
            for (int iter = 0; iter < 4; iter++) {
                int g = sub * 4 + iter;
                gload_lds16(wp + (size_t)(bcol + g * 16) * 2048 + k0 + bks,
                            bbase + (sub * 256 + iter * 64) * 16);
            }
            // unpack 16 bits -> 16 i8 (0/1): spread 4 bits to 4 bytes via mul
            uint4 u0, u1;
            {
                unsigned int b0 = bits0, b1 = bits1;
                u0.x = (((b0 >> 0)  & 0xFu) * 0x00204081u) & 0x01010101u;
                u0.y = (((b0 >> 4)  & 0xFu) * 0x00204081u) & 0x01010101u;
                u0.z = (((b0 >> 8)  & 0xFu) * 0x00204081u) & 0x01010101u;
                u0.w = (((b0 >> 12) & 0xFu) * 0x00204081u) & 0x01010101u;
                u1.x = (((b1 >> 0)  & 0xFu) * 0x00204081u) & 0x01010101u;
                u1.y = (((b1 >> 4)  & 0xFu) * 0x00204081u) & 0x01010101u;
                u1.z = (((b1 >> 8)  & 0xFu) * 0x00204081u) & 0x01010101u;
                u1.w = (((b1 >> 12) & 0xFu) * 0x00204081u) & 0x01010101u;
            }
            *(uint4*)aw0 = u0;
            *(uint4*)aw1 = u1;
            __syncthreads();                   // staging (vmcnt+lgkm) complete

            v4i a[4];
            #pragma unroll
            for (int m = 0; m < 4; m++)
                a[m] = *(const v4i*)&As8[(((wr * 4 + m) * 4 + lg) * 16 + lr) * 16];
            #pragma unroll
            for (int n = 0; n < 4; n++) {
                v4i b0 = *(const v4i*)&Bs8[0][(((wc * 4 + n) * 4 + lg) * 16 + lr) * 16];
                v4i b1 = *(const v4i*)&Bs8[1][(((wc * 4 + n) * 4 + lg) * 16 + lr) * 16];
                #pragma unroll
                for (int m = 0; m < 4; m++) {
                    acc0[m][n] = __builtin_amdgcn_mfma_i32_16x16x64_i8(
                                     a[m], b0, acc0[m][n], 0, 0, 0);
                    acc1[m][n] = __builtin_amdgcn_mfma_i32_16x16x64_i8(
                                     a[m], b1, acc1[m][n], 0, 0, 0);
                }
            }
        }
        // combine: scales 2^-5 * 2^-7(s+1) -> 2^-12, 2^-19, 2^-26, 2^-33
        const float sA = pass ? 0x1p-26f : 0x1p-12f;
        const float sB = pass ? 0x1p-33f : 0x1p-19f;
        #pragma unroll
        for (int m = 0; m < 4; m++)
            #pragma unroll
            for (int n = 0; n < 4; n++)
                #pragma unroll
                for (int e = 0; e < 4; e++) {
                    master[m][n][e] = fmaf(sA, (float)acc0[m][n][e], master[m][n][e]);
                    master[m][n][e] = fmaf(sB, (float)acc1[m][n][e], master[m][n][e]);
                }
    }

    // epilogue: C/D layout col=lane&15, row=(lane>>4)*4+q  (dtype-independent)
    #pragma unroll
    for (int m = 0; m < 4; m++) {
        int row = row0 + wr * 64 + m * 16 + (lg << 2);
        #pragma unroll
        for (int n = 0; n < 4; n++) {
            int col = col0 + wc * 64 + n * 16 + lr;
            float bv = bias[col];
            #pragma unroll
            for (int q2 = 0; q2 < 4; q2++)
                C[(size_t)(row + q2) * OUT + col] = master[m][n][q2] + bv;
        }
    }
}

// ---------------- rec2 chunk: layer-2 recurrence over 64 tau steps ---------
__global__ __launch_bounds__(256)
void rec2_chunk(const float* __restrict__ Z2c, float* __restrict__ m_state,
                float* __restrict__ s_state, float* __restrict__ out,
                int tau0, int last)
{
    int idx = blockIdx.x * 256 + threadIdx.x;   // b*OUT + o
    int o = idx & (OUT - 1);
    int b = idx >> 10;
    float m, s;
    if (tau0 == 0) { m = 0.f; s = 0.f; }
    else           { m = m_state[idx]; s = s_state[idx]; }
    float acc = 0.f;
    for (int tl = 0; tl < CHUNK; ++tl) {
        float zv = Z2c[((size_t)(tl * B + b)) * OUT + o];
        m = m * DECAY * (1.f - s) + zv;
        s = (m > THRESH) ? 1.f : 0.f;
        if (tau0 + tl >= TAU - 16) acc += s;
    }
    m_state[idx] = m;
    s_state[idx] = s;
    if (last) out[idx] = acc;
}

extern "C" void kernel_launch(void* const* d_in, const int* in_sizes, int n_in,
                              void* d_out, int out_size, void* d_ws, size_t ws_size,
                              hipStream_t stream)
{
    const float* x     = (const float*)d_in[0];
    const float* fc1_w = (const float*)d_in[1];
    const float* fc1_b = (const float*)d_in[2];
    const float* fc2_w = (const float*)d_in[3];
    const float* fc2_b = (const float*)d_in[4];
    float* out = (float*)d_out;

    char* ws = (char*)d_ws;
    float* Z1  = (float*)ws;                          // 16.8 MB, dead after rec1
    float* Z2c = (float*)ws;                          // 33.5 MB, chunk phase (alias)
    unsigned long long* Sbits = (unsigned long long*)(ws + 33554432);      // 8.4 MB
    signed char* W2q = (signed char*)(ws + 33554432 + 8388608);            // 4x2 MB i8
    float* m_state = (float*)(ws + 33554432 + 8388608 + 4 * 2097152);      // 0.5 MB
    float* s_state = m_state + B * OUT;                                    // 0.5 MB

    wsplit_i8<<<(OUT * HID / 4) / 256, 256, 0, stream>>>(fc2_w, W2q);

    // GEMM1 v3: 64x64 tiles, BK=32, conflict-free staging; bit-identical Z1
    {
        dim3 grid(HID / 64, (B * T) / 64);
        gemm1_f32v3<<<grid, 256, 0, stream>>>(x, fc1_w, fc1_b, Z1, B * T, HID, IN);
    }
    rec1<<<(B * HID) / 256, 256, 0, stream>>>(Z1, Sbits);

    const unsigned char* Sbytes = (const unsigned char*)Sbits;
    for (int c = 0; c < TAU / CHUNK; ++c) {
        dim3 grid(OUT / 128, (CHUNK * B) / 128);
        gemm2_i8<<<grid, 256, 0, stream>>>(Sbytes, W2q, fc2_b, Z2c,
                                           c * CHUNK * B);
        rec2_chunk<<<(B * OUT) / 256, 256, 0, stream>>>(
            Z2c, m_state, s_state, out, c * CHUNK, (c == TAU / CHUNK - 1) ? 1 : 0);
    }
}